// Round 5
// baseline (5377.586 us; speedup 1.0000x reference)
//
#include <hip/hip_runtime.h>
#include <hip/hip_fp16.h>

#define TSEQ 1024
#define NBATCH 256
#define HD 256
#define ID 128
#define ODIM 128

typedef _Float16 f16;
typedef _Float16 f16x8 __attribute__((ext_vector_type(8)));
typedef float f32x4 __attribute__((ext_vector_type(4)));
typedef unsigned long long ull;

// ---------------------------------------------------------------------------
// K0: pack recurrent + input weights into fp16, row order n' = j*256 + g*64 + uu
// ---------------------------------------------------------------------------
__global__ void pack_weights(
    const float* __restrict__ Wgh, const float* __restrict__ Wih,
    const float* __restrict__ Wfh, const float* __restrict__ Woh,
    const float* __restrict__ Wgx, const float* __restrict__ Wix,
    const float* __restrict__ Wfx, const float* __restrict__ Wox,
    const float* __restrict__ bgx, const float* __restrict__ bix,
    const float* __restrict__ bfx, const float* __restrict__ box,
    f16* __restrict__ Whcat, f16* __restrict__ Wxcat, float* __restrict__ bcat)
{
    const int np = blockIdx.x;            // 0..1023  (row n')
    const int g  = (np >> 6) & 3;         // gate
    const int j  = np >> 8;               // hidden slice
    const int uu = np & 63;
    const int u  = j * 64 + uu;           // global hidden unit
    const float* Wh = (g == 0) ? Wgh : (g == 1) ? Wih : (g == 2) ? Wfh : Woh;
    const float* Wx = (g == 0) ? Wgx : (g == 1) ? Wix : (g == 2) ? Wfx : Wox;
    const float* bx = (g == 0) ? bgx : (g == 1) ? bix : (g == 2) ? bfx : box;
    const int k = threadIdx.x;            // 0..255
    Whcat[np * 256 + k] = (f16)Wh[u * 256 + k];
    if (k < ID) Wxcat[np * ID + k] = (f16)Wx[u * ID + k];
    if (k == 0) bcat[np] = bx[u];
}

// ---------------------------------------------------------------------------
// K2: persistent fused recurrence. 64 WGs x 256 threads.
// WG = (grp = bid>>2 [16-batch tile], j = bid&3 [64-unit slice]).
// R3's proven sc1 (device-scope, cache-bypassing) exchange, with three fixes:
//  (1) h published via LDS transpose -> 8B coalesced sc1 stores (was 1024x2B
//      scattered stores whose ack-drain dominated the release vmcnt(0)),
//  (2) all 16 flags of a group packed in ONE 64B line -> the 16-lane poll is
//      a single coalesced IF transaction per iteration,
//  (3) x(t+1) prefetch issued AFTER the release so vmcnt(0) doesn't wait it.
// MFMA 16x16x32 f16 layouts:
//   A[m = lane&15][k = (lane>>4)*8 + e]
//   B[n = lane&15][k = (lane>>4)*8 + e]
//   D[m = (lane>>4)*4 + r][n = lane&15]
// ---------------------------------------------------------------------------
__global__ __launch_bounds__(256, 1) void lstm_rec(
    const float* __restrict__ x,
    const f16* __restrict__ Whcat,
    const f16* __restrict__ Wxcat,
    const float* __restrict__ bcat,
    f16* __restrict__ hbuf,     // [2][NBATCH][HD] fp16 parity double-buffer
    float* __restrict__ hT,     // [NBATCH][HD] fp32 final h
    int* __restrict__ flags)    // [16 groups][16 ints] one 64B line per group
{
    __shared__ f16 h_st[16 * 64];   // [row 0..15][local unit 0..63]

    const int tid  = threadIdx.x;
    const int lane = tid & 63;
    const int w    = tid >> 6;      // wave 0..3 -> units [w*16, w*16+16)
    const int q    = lane >> 4;
    const int n    = lane & 15;
    const int bid  = blockIdx.x;
    const int grp  = bid >> 2;      // batch-tile group
    const int j    = bid & 3;       // hidden slice
    const int b0   = grp * 16;

    // ---- persistent weight fragments ----
    f16x8 wh[4][8];   // [gate][kk] recurrent, K=256 -> 8 MFMA k-steps
    f16x8 wx[4][4];   // [gate][k4] input,     K=128 -> 4 MFMA k-steps
    float bias[4];
#pragma unroll
    for (int g = 0; g < 4; ++g) {
        const int row = j * 256 + g * 64 + w * 16 + n;
        bias[g] = bcat[row];
#pragma unroll
        for (int kk = 0; kk < 8; ++kk)
            wh[g][kk] = *(const f16x8*)&Whcat[row * 256 + kk * 32 + q * 8];
#pragma unroll
        for (int k4 = 0; k4 < 4; ++k4)
            wx[g][k4] = *(const f16x8*)&Wxcat[row * ID + k4 * 32 + q * 8];
    }

    float c[4] = {0.f, 0.f, 0.f, 0.f};     // cell state (b = b0+q*4+r, u = uglob)
    const int uglob = j * 64 + w * 16 + n;
    const int myflag   = grp * 16 + j * 4 + w;    // written by this WG's wave w
    const int pollflag = grp * 16 + tid;          // tid<16 polls all 16 producers

    // wide-store assignment: thread -> (row rr, 4-unit chunk cc)
    const int rr = tid >> 4;        // 0..15 (wave w covers rows w*4..w*4+3)
    const int cc = tid & 15;        // 0..15

    // ---- prefetch x(0) ----
    const float* xrow = &x[(size_t)(b0 + n) * TSEQ * ID];
    float4 xr[8];
#pragma unroll
    for (int k4 = 0; k4 < 4; ++k4) {
        xr[k4 * 2]     = *(const float4*)&xrow[k4 * 32 + q * 8];
        xr[k4 * 2 + 1] = *(const float4*)&xrow[k4 * 32 + q * 8 + 4];
    }

    for (int t = 0; t < TSEQ; ++t) {
        // ---- convert x(t) to fp16 A-fragments ----
        f16x8 xa[4];
#pragma unroll
        for (int k4 = 0; k4 < 4; ++k4) {
            const float* f0 = (const float*)&xr[k4 * 2];
            const float* f1 = (const float*)&xr[k4 * 2 + 1];
#pragma unroll
            for (int e = 0; e < 4; ++e) {
                xa[k4][e]     = (f16)f0[e];
                xa[k4][4 + e] = (f16)f1[e];
            }
        }

        // ---- x-projection MFMAs (independent of h) ----
        f32x4 acc[4];
#pragma unroll
        for (int g = 0; g < 4; ++g) {
            f32x4 av = {bias[g], bias[g], bias[g], bias[g]};
            acc[g] = av;
        }
#pragma unroll
        for (int k4 = 0; k4 < 4; ++k4)
#pragma unroll
            for (int g = 0; g < 4; ++g)
                acc[g] = __builtin_amdgcn_mfma_f32_16x16x32_f16(xa[k4], wx[g][k4], acc[g], 0, 0, 0);

        // ---- wait for h(t-1): single coalesced poll line per group ----
        if (t > 0) {
            if (tid < 16) {
                while (__hip_atomic_load(&flags[pollflag], __ATOMIC_RELAXED,
                                         __HIP_MEMORY_SCOPE_AGENT) < t)
                    __builtin_amdgcn_s_sleep(1);
            }
            __syncthreads();   // orders the h loads below after flag confirmation
            const ull* hp = (const ull*)
                &hbuf[(size_t)(((t - 1) & 1) * NBATCH + b0 + n) * HD];
            f16x8 ha[8];
#pragma unroll
            for (int kk = 0; kk < 8; ++kk) {
                union { ull u[2]; f16x8 v; } hu;
                hu.u[0] = __hip_atomic_load(hp + kk * 8 + q * 2,     __ATOMIC_RELAXED,
                                            __HIP_MEMORY_SCOPE_AGENT);
                hu.u[1] = __hip_atomic_load(hp + kk * 8 + q * 2 + 1, __ATOMIC_RELAXED,
                                            __HIP_MEMORY_SCOPE_AGENT);
                ha[kk] = hu.v;
            }
#pragma unroll
            for (int kk = 0; kk < 8; ++kk)
#pragma unroll
                for (int g = 0; g < 4; ++g)
                    acc[g] = __builtin_amdgcn_mfma_f32_16x16x32_f16(ha[kk], wh[g][kk], acc[g], 0, 0, 0);
        }

        // ---- gates, cell/hidden update ----
        float hh[4];
#pragma unroll
        for (int r = 0; r < 4; ++r) {
            const float gp_ = acc[0][r], ip_ = acc[1][r], fp_ = acc[2][r], op_ = acc[3][r];
            const float gg = 1.f - 2.f / (1.f + __expf(2.f * gp_));
            const float ii = 1.f / (1.f + __expf(-ip_));
            const float ff = 1.f / (1.f + __expf(-fp_));
            const float oo = 1.f / (1.f + __expf(-op_));
            c[r] = gg * ii + c[r] * ff;
            hh[r] = (1.f - 2.f / (1.f + __expf(2.f * c[r]))) * oo;
        }

        if (t < TSEQ - 1) {
            // ---- publish: LDS transpose -> coalesced 8B sc1 stores ----
#pragma unroll
            for (int r = 0; r < 4; ++r)
                h_st[(q * 4 + r) * 64 + w * 16 + n] = (f16)hh[r];
            __syncthreads();
            {
                ull v = *(const ull*)&h_st[rr * 64 + cc * 4];
                ull* dst = (ull*)&hbuf[(size_t)((t & 1) * NBATCH + b0 + rr) * HD + j * 64 + cc * 4];
                __hip_atomic_store(dst, v, __ATOMIC_RELAXED, __HIP_MEMORY_SCOPE_AGENT);
            }
            // ---- release: drain this wave's h stores, then flag store ----
            __atomic_signal_fence(__ATOMIC_SEQ_CST);
            __builtin_amdgcn_s_waitcnt(0x0F70);             // vmcnt(0)
            __atomic_signal_fence(__ATOMIC_SEQ_CST);
            if (lane == 0)
                __hip_atomic_store(&flags[myflag], t + 1, __ATOMIC_RELAXED,
                                   __HIP_MEMORY_SCOPE_AGENT);
            // ---- x(t+1) prefetch AFTER release (overlaps next poll) ----
            const float* xp = &xrow[(size_t)(t + 1) * ID];
#pragma unroll
            for (int k4 = 0; k4 < 4; ++k4) {
                xr[k4 * 2]     = *(const float4*)&xp[k4 * 32 + q * 8];
                xr[k4 * 2 + 1] = *(const float4*)&xp[k4 * 32 + q * 8 + 4];
            }
        } else {
            // final step: write fp32 h_T directly
#pragma unroll
            for (int r = 0; r < 4; ++r)
                hT[(size_t)(b0 + q * 4 + r) * HD + uglob] = hh[r];
        }
    }
}

// ---------------------------------------------------------------------------
// K3: out[b][o] = sum_u hT[b][u] * Wp[o][u] + bp[o]   (fp32)
// ---------------------------------------------------------------------------
__global__ void out_proj(const float* __restrict__ hT, const float* __restrict__ Wp,
                         const float* __restrict__ bp, float* __restrict__ out)
{
    const int b = blockIdx.x;       // 0..255
    const int o = threadIdx.x;      // 0..127
    __shared__ float hrow[HD];
    for (int u = threadIdx.x; u < HD; u += ODIM) hrow[u] = hT[b * HD + u];
    __syncthreads();
    float s = bp[o];
    const float* wr = &Wp[o * HD];
#pragma unroll 8
    for (int u = 0; u < HD; ++u) s += hrow[u] * wr[u];
    out[b * ODIM + o] = s;
}

// ---------------------------------------------------------------------------
extern "C" void kernel_launch(void* const* d_in, const int* in_sizes, int n_in,
                              void* d_out, int out_size, void* d_ws, size_t ws_size,
                              hipStream_t stream) {
    const float* x   = (const float*)d_in[0];
    const float* Wgx = (const float*)d_in[1];
    const float* bgx = (const float*)d_in[2];
    const float* Wgh = (const float*)d_in[3];
    const float* Wix = (const float*)d_in[4];
    const float* bix = (const float*)d_in[5];
    const float* Wih = (const float*)d_in[6];
    const float* Wfx = (const float*)d_in[7];
    const float* bfx = (const float*)d_in[8];
    const float* Wfh = (const float*)d_in[9];
    const float* Wox = (const float*)d_in[10];
    const float* box = (const float*)d_in[11];
    const float* Woh = (const float*)d_in[12];
    const float* Wp  = (const float*)d_in[13];
    const float* bp  = (const float*)d_in[14];
    float* out = (float*)d_out;

    char* ws = (char*)d_ws;
    f16*   Whcat = (f16*)(ws);                         // 1024*256*2    = 524288
    f16*   Wxcat = (f16*)(ws + 524288);                // 1024*128*2    = 262144
    float* bcat  = (float*)(ws + 786432);              // 1024*4        = 4096
    f16*   hbuf  = (f16*)(ws + 790528);                // 2*256*256*2   = 262144
    float* hT    = (float*)(ws + 1052672);             // 256*256*4     = 262144
    int*   flags = (int*)(ws + 1314816);               // 16*16*4       = 1024

    hipMemsetAsync(flags, 0, 16 * 16 * sizeof(int), stream);
    pack_weights<<<1024, 256, 0, stream>>>(Wgh, Wih, Wfh, Woh,
                                           Wgx, Wix, Wfx, Wox,
                                           bgx, bix, bfx, box,
                                           Whcat, Wxcat, bcat);
    lstm_rec<<<64, 256, 0, stream>>>(x, Whcat, Wxcat, bcat, hbuf, hT, flags);
    out_proj<<<NBATCH, ODIM, 0, stream>>>(hT, Wp, bp, out);
}